// Round 3
// baseline (296.607 us; speedup 1.0000x reference)
//
#include <hip/hip_runtime.h>
#include <hip/hip_bf16.h>

#define N_ATOMS 10000
#define N_EDGES 160000
#define N_SPECIES 8
#define N_STRUCT 8
#define PI_F 3.14159265358979323846f

// ---------------- setup kernels ----------------

__global__ void zero_kernel(int* cnt, float* accum) {
    int i = blockIdx.x * blockDim.x + threadIdx.x;
    if (i < N_ATOMS) cnt[i] = 0;
    if (i < N_STRUCT) accum[i] = 0.0f;
}

__global__ void hist_kernel(const int* __restrict__ receivers, int* __restrict__ cnt) {
    int e = blockIdx.x * blockDim.x + threadIdx.x;
    if (e < N_EDGES) atomicAdd(&cnt[receivers[e]], 1);
}

__global__ void scan_kernel(const int* __restrict__ cnt, int* __restrict__ row_ptr) {
    __shared__ int buf[1024];
    __shared__ int carry;
    int t = threadIdx.x;
    if (t == 0) { carry = 0; row_ptr[0] = 0; }
    __syncthreads();
    for (int base = 0; base < N_ATOMS; base += 1024) {
        int x = (base + t < N_ATOMS) ? cnt[base + t] : 0;
        buf[t] = x;
        __syncthreads();
        for (int off = 1; off < 1024; off <<= 1) {
            int v = (t >= off) ? buf[t - off] : 0;
            __syncthreads();
            buf[t] += v;
            __syncthreads();
        }
        int inc = buf[t] + carry;
        if (base + t < N_ATOMS) row_ptr[base + t + 1] = inc;
        __syncthreads();
        if (t == 1023) carry = inc;
        __syncthreads();
    }
}

__global__ void cursor_kernel(const int* __restrict__ row_ptr, int* __restrict__ cursor) {
    int i = blockIdx.x * blockDim.x + threadIdx.x;
    if (i < N_ATOMS) cursor[i] = row_ptr[i];
}

__global__ void scatter_kernel(const int* __restrict__ receivers, int* __restrict__ cursor,
                               int* __restrict__ edge_idx) {
    int e = blockIdx.x * blockDim.x + threadIdx.x;
    if (e < N_EDGES) {
        int p = atomicAdd(&cursor[receivers[e]], 1);
        edge_idx[p] = e;
    }
}

__global__ void emb_kernel(const float* __restrict__ embed, const int* __restrict__ species,
                           float* __restrict__ h0) {
    int i = blockIdx.x * blockDim.x + threadIdx.x;
    if (i < N_ATOMS * 16) {
        int a = i >> 4, c = i & 15;
        h0[i] = embed[species[a] * 16 + c];
    }
}

// ---------------- edge geometry: sh[E,16], R[E,16] ----------------

__global__ void edge_geom(const float* __restrict__ pos, const float* __restrict__ W_rad,
                          const int* __restrict__ senders, const int* __restrict__ receivers,
                          float* __restrict__ sh, float* __restrict__ Rr) {
    int e = blockIdx.x * blockDim.x + threadIdx.x;
    if (e >= N_EDGES) return;
    int s = senders[e], rc = receivers[e];
    float dx = pos[rc * 3 + 0] - pos[s * 3 + 0];
    float dy = pos[rc * 3 + 1] - pos[s * 3 + 1];
    float dz = pos[rc * 3 + 2] - pos[s * 3 + 2];
    float r = sqrtf(dx * dx + dy * dy + dz * dz);
    float rr = fmaxf(r, 1e-6f);
    float inv = 1.0f / rr;
    float x = dx * inv, y = dy * inv, z = dz * inv;
    float x2 = x * x, y2 = y * y, z2 = z * z;
    float* she = sh + (size_t)e * 16;
    she[0]  = 0.28209479f;
    she[1]  = 0.48860251f * y;
    she[2]  = 0.48860251f * z;
    she[3]  = 0.48860251f * x;
    she[4]  = 1.09254843f * x * y;
    she[5]  = 1.09254843f * y * z;
    she[6]  = 0.31539157f * (3.0f * z2 - 1.0f);
    she[7]  = 1.09254843f * x * z;
    she[8]  = 0.54627422f * (x2 - y2);
    she[9]  = 0.59004359f * y * (3.0f * x2 - y2);
    she[10] = 2.89061144f * x * y * z;
    she[11] = 0.45704579f * y * (5.0f * z2 - 1.0f);
    she[12] = 0.37317633f * z * (5.0f * z2 - 3.0f);
    she[13] = 0.45704579f * x * (5.0f * z2 - 1.0f);
    she[14] = 1.44530572f * z * (x2 - y2);
    she[15] = 0.59004359f * x * (x2 - 3.0f * y2);
    // radial: Bessel basis * cosine cutoff, projected by W_rad [4,8,4]
    float fc = 0.5f * (cosf(PI_F * fminf(r * 0.2f, 1.0f)) + 1.0f);
    const float c0 = 0.6324555320336759f; // sqrt(2/5)
    float bfv[8];
    #pragma unroll
    for (int n = 0; n < 8; ++n)
        bfv[n] = c0 * sinf((float)(n + 1) * PI_F * rr * 0.2f) * inv * fc;
    float* Re = Rr + (size_t)e * 16;
    #pragma unroll
    for (int l = 0; l < 4; ++l) {
        #pragma unroll
        for (int n = 0; n < 4; ++n) {
            float acc = 0.0f;
            #pragma unroll
            for (int b = 0; b < 8; ++b) acc = fmaf(bfv[b], W_rad[l * 32 + b * 4 + n], acc);
            Re[l * 4 + n] = acc;
        }
    }
}

// ---------------- fused MP layer: one atom per 256-thread block ----------------
// thread t -> (m = t>>4, c = t&15); registers hold A[m, n=0..3, c]

__global__ __launch_bounds__(256) void mp_layer(
    const int* __restrict__ row_ptr, const int* __restrict__ edge_idx,
    const int* __restrict__ senders,
    const float* __restrict__ sh, const float* __restrict__ Rr,
    const float* __restrict__ h_in, const float* __restrict__ W_inv,
    const float* __restrict__ cemb, float* __restrict__ h_out,
    const float* __restrict__ w_out, const float* __restrict__ comp_w,
    const int* __restrict__ species, const int* __restrict__ sids,
    float* __restrict__ accum, int do_energy)
{
    __shared__ float s_sl[256];
    __shared__ alignas(16) float s_r[256];
    __shared__ float s_hs[256];
    __shared__ float s_sq[1024];
    __shared__ float s_inv[256];
    __shared__ float s_red[256];

    const int atom = blockIdx.x;
    const int t = threadIdx.x;
    const int m = t >> 4, c = t & 15;
    const int l_of_m[16] = {0, 1, 1, 1, 2, 2, 2, 2, 2, 3, 3, 3, 3, 3, 3, 3};
    const int l = l_of_m[m];

    const int start = row_ptr[atom];
    const int end = row_ptr[atom + 1];

    float a0 = 0.f, a1 = 0.f, a2 = 0.f, a3 = 0.f;

    for (int base = start; base < end; base += 16) {
        int nb = min(16, end - base);
        // stage up to 16 edges: slot = m, element j = c
        if (m < nb) {
            int e = edge_idx[base + m];
            int s = senders[e];
            s_sl[t] = sh[(size_t)e * 16 + c];
            s_r[t]  = Rr[(size_t)e * 16 + c];
            s_hs[t] = h_in[s * 16 + c];
        }
        __syncthreads();
        for (int q = 0; q < nb; ++q) {
            float w = s_sl[q * 16 + m] * s_hs[q * 16 + c];
            const float4 rl = *(const float4*)&s_r[q * 16 + l * 4];
            a0 = fmaf(w, rl.x, a0);
            a1 = fmaf(w, rl.y, a1);
            a2 = fmaf(w, rl.z, a2);
            a3 = fmaf(w, rl.w, a3);
        }
        __syncthreads();
    }

    // inv[l,n,c] = sum_m_in_l A^2 / sqrt(2l+1)
    s_sq[m * 64 + 0 * 16 + c] = a0 * a0;
    s_sq[m * 64 + 1 * 16 + c] = a1 * a1;
    s_sq[m * 64 + 2 * 16 + c] = a2 * a2;
    s_sq[m * 64 + 3 * 16 + c] = a3 * a3;
    __syncthreads();
    {
        const int l2 = t >> 6, n = (t >> 4) & 3, c2 = t & 15;
        const float sc[4] = {1.0f, 0.57735026918962576f, 0.44721359549995794f, 0.37796447300922720f};
        float sum = 0.f;
        const int m0 = l2 * l2, m1 = m0 + 2 * l2;
        for (int mm = m0; mm <= m1; ++mm) sum += s_sq[mm * 64 + n * 16 + c2];
        s_inv[t] = sum * sc[l2];   // ktot == t == l*64 + n*16 + c
    }
    __syncthreads();

    if (!do_energy) {
        // h_new[c'] = (sum_k inv[k] * W_inv[k,c']) * cemb[atom,c']
        const int cp = t & 15, g = t >> 4;
        float partial = 0.f;
        #pragma unroll
        for (int j = 0; j < 16; ++j) {
            int k = g * 16 + j;
            partial = fmaf(s_inv[k], W_inv[k * 16 + cp], partial);
        }
        s_red[t] = partial;
        __syncthreads();
        if (t < 16) {
            float sum = 0.f;
            for (int g2 = 0; g2 < 16; ++g2) sum += s_red[g2 * 16 + t];
            h_out[atom * 16 + t] = sum * cemb[atom * 16 + t];
        }
    } else {
        // e_atom = sum_k inv[k] * w_out[k] + comp_w[species]; segment-sum by structure
        s_red[t] = s_inv[t] * w_out[t];
        __syncthreads();
        for (int off = 128; off > 0; off >>= 1) {
            if (t < off) s_red[t] += s_red[t + off];
            __syncthreads();
        }
        if (t == 0) {
            float e_atom = s_red[0] + comp_w[species[atom]];
            atomicAdd(&accum[sids[atom]], e_atom);
        }
    }
}

__global__ void out_kernel(const float* __restrict__ accum, float* __restrict__ out) {
    int t = threadIdx.x;
    if (t < N_STRUCT) out[t] = accum[t];
}

// ---------------- launch ----------------

extern "C" void kernel_launch(void* const* d_in, const int* in_sizes, int n_in,
                              void* d_out, int out_size, void* d_ws, size_t ws_size,
                              hipStream_t stream) {
    const float* positions = (const float*)d_in[0];
    const float* embed     = (const float*)d_in[1];
    const float* W_rad     = (const float*)d_in[2];
    const float* W_inv1    = (const float*)d_in[3];
    const float* W_inv2    = (const float*)d_in[4];
    const float* w_out     = (const float*)d_in[5];
    const float* comp_w    = (const float*)d_in[6];
    const int* senders    = (const int*)d_in[7];
    const int* receivers  = (const int*)d_in[8];
    const int* species    = (const int*)d_in[9];
    const int* sids       = (const int*)d_in[10];
    float* out = (float*)d_out;

    char* ws = (char*)d_ws;
    size_t off = 0;
    auto alloc = [&](size_t bytes) -> void* {
        void* p = ws + off;
        off = (off + bytes + 255) & ~(size_t)255;
        return p;
    };
    float* sh       = (float*)alloc((size_t)N_EDGES * 16 * 4);
    float* Rr       = (float*)alloc((size_t)N_EDGES * 16 * 4);
    float* h0       = (float*)alloc((size_t)N_ATOMS * 16 * 4);
    float* h1       = (float*)alloc((size_t)N_ATOMS * 16 * 4);
    int*   cnt      = (int*)alloc((size_t)N_ATOMS * 4);
    int*   row_ptr  = (int*)alloc((size_t)(N_ATOMS + 1) * 4);
    int*   cursor   = (int*)alloc((size_t)N_ATOMS * 4);
    int*   edge_idx = (int*)alloc((size_t)N_EDGES * 4);
    float* accum    = (float*)alloc(8 * 4);

    const int EB = (N_EDGES + 255) / 256;        // 625
    const int AB = (N_ATOMS + 255) / 256;        // 40
    const int HB = (N_ATOMS * 16 + 255) / 256;   // 625

    zero_kernel<<<AB, 256, 0, stream>>>(cnt, accum);
    edge_geom<<<EB, 256, 0, stream>>>(positions, W_rad, senders, receivers, sh, Rr);
    hist_kernel<<<EB, 256, 0, stream>>>(receivers, cnt);
    scan_kernel<<<1, 1024, 0, stream>>>(cnt, row_ptr);
    cursor_kernel<<<AB, 256, 0, stream>>>(row_ptr, cursor);
    scatter_kernel<<<EB, 256, 0, stream>>>(receivers, cursor, edge_idx);
    emb_kernel<<<HB, 256, 0, stream>>>(embed, species, h0);

    // layer 1: h_in = cemb = h0, output h1
    mp_layer<<<N_ATOMS, 256, 0, stream>>>(row_ptr, edge_idx, senders, sh, Rr,
                                          h0, W_inv1, h0, h1,
                                          w_out, comp_w, species, sids, accum, 0);
    // layer 2: h_in = h1, energy path
    mp_layer<<<N_ATOMS, 256, 0, stream>>>(row_ptr, edge_idx, senders, sh, Rr,
                                          h1, W_inv2, h0, h1,
                                          w_out, comp_w, species, sids, accum, 1);

    out_kernel<<<1, 64, 0, stream>>>(accum, out);
}